// Round 1
// baseline (253.161 us; speedup 1.0000x reference)
//
#include <hip/hip_runtime.h>
#include <stdint.h>
#include <stddef.h>

#define DIM 768

typedef short short8 __attribute__((ext_vector_type(8)));
typedef float f32x4 __attribute__((ext_vector_type(4)));
typedef unsigned short ushortx4 __attribute__((ext_vector_type(4)));

__device__ inline unsigned short f2bf_rne(float f) {
    union { float f; unsigned u; } x; x.f = f;
    unsigned r = x.u + 0x7fffu + ((x.u >> 16) & 1u);
    return (unsigned short)(r >> 16);
}

__device__ inline void gload_lds16(const void* g, void* l) {
    __builtin_amdgcn_global_load_lds((const __attribute__((address_space(1))) void*)g,
                                     (__attribute__((address_space(3))) void*)l, 16, 0, 0);
}

// Kernel 1: W [K][N] fp32 -> Bt [N][K] bf16 via LDS transpose. Also zeroes the
// compaction counter (must precede gather_kernel's atomics; same-stream ordering).
__global__ __launch_bounds__(256) void convw_kernel(
    const float* __restrict__ w, unsigned short* __restrict__ Bt, int* __restrict__ counter)
{
    if (blockIdx.x == 0 && blockIdx.y == 0 && threadIdx.x == 0) *counter = 0;
    __shared__ unsigned short t[64][65];
    const int k0 = blockIdx.x * 64, n0 = blockIdx.y * 64;
    const int tid = threadIdx.x;
#pragma unroll
    for (int p = 0; p < 16; ++p) {
        int e = p * 256 + tid;
        int r = e >> 6, c = e & 63;
        t[c][r] = f2bf_rne(w[(size_t)(k0 + r) * DIM + n0 + c]);
    }
    __syncthreads();
#pragma unroll
    for (int p = 0; p < 16; ++p) {
        int e = p * 256 + tid;
        int r = e >> 6, c = e & 63;
        Bt[(size_t)(n0 + r) * DIM + k0 + c] = t[r][c];
    }
}

// Kernel 2: streaming gather + partition.
// Block handles 32 tokens. need==0: copy fp32 emb row straight to out (exact).
// need==1: convert row to bf16 into compacted Ac[slot], record idx[slot]=token pos.
// One ballot + one atomicAdd per block assigns slots.
__global__ __launch_bounds__(256) void gather_kernel(
    const int* __restrict__ token,
    const int* __restrict__ need_mapper,
    const float* __restrict__ emb,
    unsigned short* __restrict__ Ac,
    int* __restrict__ idx,
    int* __restrict__ counter,
    float* __restrict__ out)
{
    __shared__ int tok_s[32];
    __shared__ int slot_s[32];
    const int tid = threadIdx.x;
    const int base = blockIdx.x * 32;

    if (tid < 64) {
        int t = 0, nm = 0;
        if (tid < 32) { t = token[base + tid]; nm = need_mapper[t]; }
        unsigned long long m = __ballot(nm != 0);
        int bb = 0;
        if (tid == 0) { int c = __popcll(m); if (c) bb = atomicAdd(counter, c); }
        bb = __shfl(bb, 0);
        if (tid < 32) {
            tok_s[tid] = t;
            int s = -1;
            if (nm) {
                s = bb + __popcll(m & ((1ull << tid) - 1ull));
                idx[s] = base + tid;
            }
            slot_s[tid] = s;
        }
    }
    __syncthreads();

    const int wave = tid >> 6, lane = tid & 63;
    for (int tk = wave; tk < 32; tk += 4) {         // wave-uniform branch below
        const float* src = emb + (size_t)tok_s[tk] * DIM;
        const int slot = slot_s[tk];
        if (slot < 0) {
            float* dst = out + (size_t)(base + tk) * DIM;
#pragma unroll
            for (int p = 0; p < 3; ++p)
                *(f32x4*)(dst + p * 256 + lane * 4) = *(const f32x4*)(src + p * 256 + lane * 4);
        } else {
            unsigned short* dst = Ac + (size_t)slot * DIM;
#pragma unroll
            for (int p = 0; p < 3; ++p) {
                f32x4 v = *(const f32x4*)(src + p * 256 + lane * 4);
                ushortx4 h;
                h[0] = f2bf_rne(v[0]); h[1] = f2bf_rne(v[1]);
                h[2] = f2bf_rne(v[2]); h[3] = f2bf_rne(v[3]);
                *(ushortx4*)(dst + p * 256 + lane * 4) = h;
            }
        }
    }
}

// Kernel 3: dense bf16 GEMM over compacted rows only (~half of 16384).
// 128x128 tile, BK=32, 4 waves, double-buffered LDS (stage t+1 || compute t,
// ONE barrier per K-step). A and B both [row][32] bf16 in LDS with 16B-chunk
// XOR swizzle: slot s of row r holds source chunk s ^ ((r>>1)&3)  -> 2-way
// bank aliasing on ds_read_b128 (free). Scatter epilogue through idx + bias.
__global__ __launch_bounds__(256) void gemm_kernel(
    const unsigned short* __restrict__ Ac,
    const unsigned short* __restrict__ Bt,
    const int* __restrict__ idx,
    const int* __restrict__ counter,
    const float* __restrict__ bias,
    float* __restrict__ out)
{
    const int count = *counter;
    const int tile_m = blockIdx.x;
    if (tile_m * 128 >= count) return;
    const int tile_n = blockIdx.y;

    __shared__ unsigned short As[2][128 * 32];   // 16 KB
    __shared__ unsigned short Bs[2][128 * 32];   // 16 KB
    __shared__ int idx_s[128];

    const int tid  = threadIdx.x;
    const int wave = tid >> 6;
    const int lane = tid & 63;
    const int quad = lane >> 4;
    const int l15  = lane & 15;
    const int wm   = wave >> 1;
    const int wn   = wave & 1;

    if (tid < 128) {
        int s = tile_m * 128 + tid;
        idx_s[tid] = (s < count) ? idx[s] : 0;
    }

    // Staging: issue covers 64 rows; thread -> row tid>>2, LDS slot tid&3.
    // Source chunk for LDS slot s of row r is s ^ ((r>>1)&3).
    const int ra = tid >> 2, sa = tid & 3;
    const unsigned short* pA0 = Ac + (size_t)(tile_m * 128 + ra) * DIM + ((sa ^ ((ra >> 1) & 3)) << 3);
    const unsigned short* pA1 = Ac + (size_t)(tile_m * 128 + 64 + ra) * DIM + ((sa ^ (((64 + ra) >> 1) & 3)) << 3);
    const unsigned short* pB0 = Bt + (size_t)(tile_n * 128 + ra) * DIM + ((sa ^ ((ra >> 1) & 3)) << 3);
    const unsigned short* pB1 = Bt + (size_t)(tile_n * 128 + 64 + ra) * DIM + ((sa ^ (((64 + ra) >> 1) & 3)) << 3);

#define STAGE(b, kk) do { \
    gload_lds16(pA0 + (kk), &As[(b)][wave * 512]); \
    gload_lds16(pA1 + (kk), &As[(b)][2048 + wave * 512]); \
    gload_lds16(pB0 + (kk), &Bs[(b)][wave * 512]); \
    gload_lds16(pB1 + (kk), &Bs[(b)][2048 + wave * 512]); \
} while (0)

    f32x4 acc[4][4] = {};

#define COMPUTE(b) do { \
    short8 af[4], bf[4]; \
    _Pragma("unroll") \
    for (int i = 0; i < 4; ++i) { \
        int m = wm * 64 + i * 16 + l15; \
        af[i] = *(const short8*)(&As[(b)][m * 32 + ((quad ^ ((m >> 1) & 3)) << 3)]); \
    } \
    _Pragma("unroll") \
    for (int j = 0; j < 4; ++j) { \
        int n = wn * 64 + j * 16 + l15; \
        bf[j] = *(const short8*)(&Bs[(b)][n * 32 + ((quad ^ ((n >> 1) & 3)) << 3)]); \
    } \
    _Pragma("unroll") \
    for (int i = 0; i < 4; ++i) \
        _Pragma("unroll") \
        for (int j = 0; j < 4; ++j) \
            acc[i][j] = __builtin_amdgcn_mfma_f32_16x16x32_bf16(af[i], bf[j], acc[i][j], 0, 0, 0); \
} while (0)

    STAGE(0, 0);
    __syncthreads();            // drains vmcnt(0): buf0 ready, idx_s ready
    int cur = 0;
    for (int kk = 32; kk < DIM; kk += 32) {
        STAGE(cur ^ 1, kk);     // prefetch next K-step while computing this one
        COMPUTE(cur);
        __syncthreads();        // drains vmcnt+lgkm: next buf ready, reads done
        cur ^= 1;
    }
    COMPUTE(cur);

    // Epilogue. C/D layout: col = lane&15, row = quad*4 + reg.
    const int colg = tile_n * 128 + wn * 64 + l15;
    float bv[4];
#pragma unroll
    for (int j = 0; j < 4; ++j) bv[j] = bias[colg + j * 16];

#pragma unroll
    for (int i = 0; i < 4; ++i) {
#pragma unroll
        for (int r = 0; r < 4; ++r) {
            const int lrow = wm * 64 + i * 16 + quad * 4 + r;
            const int slot = tile_m * 128 + lrow;
            if (slot < count) {
                float* orow = out + (size_t)idx_s[lrow] * DIM + colg;
#pragma unroll
                for (int j = 0; j < 4; ++j)
                    orow[j * 16] = acc[i][j][r] + bv[j];
            }
        }
    }
#undef STAGE
#undef COMPUTE
}

extern "C" void kernel_launch(void* const* d_in, const int* in_sizes, int n_in,
                              void* d_out, int out_size, void* d_ws, size_t ws_size,
                              hipStream_t stream)
{
    const int*   token       = (const int*)d_in[0];
    const int*   need_mapper = (const int*)d_in[1];
    const float* emb         = (const float*)d_in[2];
    const float* w           = (const float*)d_in[3];
    const float* bias        = (const float*)d_in[4];
    float* out = (float*)d_out;

    const int ntok = in_sizes[0];   // 32*512 = 16384

    // Workspace layout (26.3 MB):
    //   [0, 1.18MB)            Bt   768x768 bf16
    //   [2MB, 2MB+24MB)        Ac   16384x768 bf16 (compacted rows)
    //   then idx[16384] int, then counter int
    unsigned short* Bt = (unsigned short*)d_ws;
    unsigned short* Ac = (unsigned short*)((char*)d_ws + (1u << 21));
    int* idx     = (int*)((char*)d_ws + (1u << 21) + (size_t)16384 * DIM * 2);
    int* counter = idx + 16384;

    convw_kernel<<<dim3(DIM / 64, DIM / 64), dim3(256), 0, stream>>>(w, Bt, counter);
    gather_kernel<<<dim3(ntok / 32), dim3(256), 0, stream>>>(
        token, need_mapper, emb, Ac, idx, counter, out);
    gemm_kernel<<<dim3(ntok / 128, DIM / 128), dim3(256), 0, stream>>>(
        Ac, Bt, idx, counter, bias, out);
}